// Round 7
// baseline (919.426 us; speedup 1.0000x reference)
//
#include <hip/hip_runtime.h>
#include <hip/hip_bf16.h>
#include <stdint.h>

// ---------------- constants ----------------
#define NN 50000
#define EE 800000
#define HD 128
#define ETILE 256
#define PREPB 769
#define HISTB 3125   // (EE+255)/256
#define P12B  196    // (NN+255)/256
#define SCATB 782    // (EE+1023)/1024
#define NODEB 391    // (NN+127)/128
#define XNEWB 293    // (NN*3+511)/512

typedef __attribute__((ext_vector_type(8))) short s8v;   // 8 bf16 (4 VGPRs) mfma A/B frag
typedef __attribute__((ext_vector_type(4))) short s4v;   // 4 bf16 (8B)
typedef __attribute__((ext_vector_type(4))) float f32x4; // mfma C/D frag

__device__ inline float b2f(short s) {
    unsigned u = ((unsigned)(unsigned short)s) << 16;
    return __builtin_bit_cast(float, u);
}
__device__ inline short bf16r(float f) {
    unsigned u = __builtin_bit_cast(unsigned, f);
    unsigned r = (u + 0x7fffu + ((u >> 16) & 1u)) >> 16;
    return (short)r;
}
__device__ inline s4v pack4(float a, float b, float c, float d) {
    union { __hip_bfloat162 h2[2]; s4v v; } u;
    u.h2[0] = __float22bfloat162_rn(make_float2(a, b));
    u.h2[1] = __float22bfloat162_rn(make_float2(c, d));
    return u.v;
}
__device__ inline s8v pack8(const float* v) {
    union { __hip_bfloat162 h2[4]; s8v v8; } u;
    #pragma unroll
    for (int i = 0; i < 4; i++) u.h2[i] = __float22bfloat162_rn(make_float2(v[2*i], v[2*i+1]));
    return u.v8;
}
__device__ inline float fsilu(float v) { return v / (1.f + __expf(-v)); }

__device__ inline float ldw(const void* p, long i, bool f32) {
    return f32 ? ((const float*)p)[i] : b2f(((const short*)p)[i]);
}
__device__ inline short ldb(const void* p, long i, bool f32) {
    return f32 ? bf16r(((const float*)p)[i]) : ((const short*)p)[i];
}
__device__ inline int ldi(const void* p, long i, bool i64) {
    return i64 ? (int)((const long long*)p)[i] : ((const int*)p)[i];
}

// ---------------- dtype detection ----------------
__global__ void detect_kernel(const unsigned* __restrict__ h_raw,
                              const unsigned* __restrict__ ei_raw, int* flags) {
    __shared__ int cnt_f32, cnt_nz;
    int t = threadIdx.x;
    if (t == 0) { cnt_f32 = 0; cnt_nz = 0; }
    __syncthreads();
    unsigned u = h_raw[t];
    unsigned ex = (u >> 23) & 0xFFu;
    int isf = (ex >= 100u && ex <= 150u) ? 1 : 0;
    unsigned w = ei_raw[2 * t + 1];
    int nz = (w != 0u) ? 1 : 0;
    atomicAdd(&cnt_f32, isf);
    atomicAdd(&cnt_nz, nz);
    __syncthreads();
    if (t == 0) {
        flags[0] = (cnt_f32 >= 128) ? 1 : 0;
        flags[1] = (cnt_nz < 8) ? 1 : 0;
    }
}

// ---------------- fused: prep_weights (blocks 0..768) || hist (blocks 769..3893) ----------
__global__ __launch_bounds__(256)
void prep_hist_kernel(const void* we1, const void* we2, const void* wc1,
                      const void* wn1, const void* wn2,
                      const void* be1, const void* be2, const void* bc1,
                      const void* wa, const void* ba, const void* wc2,
                      const void* bn1, const void* bn2,
                      const void* gmma, const void* beta,
                      const void* __restrict__ ei,
                      const int* __restrict__ flags,
                      short* __restrict__ we1tt, short* __restrict__ we2t,
                      short* __restrict__ wc1t, short* __restrict__ wn1t,
                      short* __restrict__ wn2t, float* __restrict__ biasbuf,
                      int* __restrict__ cnt) {
    bool f32 = flags[0] != 0;
    int b = blockIdx.x, t = threadIdx.x;
    if (b >= PREPB) {   // ---- hist part ----
        int e = (b - PREPB) * 256 + t;
        if (e < EE) atomicAdd(&cnt[ldi(ei, (long)EE + e, flags[1] != 0)], 1);
        return;
    }
    if (b < 256) {
        if (t < 128) we1tt[b * 128 + t] = ldb(we1, (long)((b < 128 ? t : t + 128)) * 128 + (b & 127), f32);
    } else if (b < 384) {
        int j = b - 256; if (t < 128) we2t[j * 128 + t] = ldb(we2, t * 128 + j, f32);
    } else if (b < 512) {
        int j = b - 384; if (t < 128) wc1t[j * 128 + t] = ldb(wc1, t * 128 + j, f32);
    } else if (b < 640) {
        int j = b - 512; wn1t[j * 256 + t] = ldb(wn1, t * 128 + j, f32);   // j in [0,128)
    } else if (b < 768) {
        int j = b - 640; if (t < 128) wn2t[j * 128 + t] = ldb(wn2, t * 128 + j, f32);
    } else if (t < 128) {
        biasbuf[t]         = ldw(be1, t, f32);
        biasbuf[128 + t]   = ldw(be2, t, f32);
        biasbuf[256 + t]   = ldw(bc1, t, f32);
        biasbuf[384 + t]   = ldw(wa, t, f32);
        biasbuf[512 + t]   = ldw(wc2, t, f32);
        biasbuf[768 + t]   = ldw(bn1, t, f32);
        biasbuf[896 + t]   = ldw(bn2, t, f32);
        biasbuf[1024 + t]  = ldw(gmma, t, f32);
        biasbuf[1152 + t]  = ldw(beta, t, f32);
        biasbuf[1280 + t]  = ldw(we1, 256 * 128 + t, f32);   // We1 dist row
        if (t == 0) biasbuf[640] = ldw(ba, 0, f32);
    }
}

// ---------------- exclusive scan of cnt[50000] -> fillptr ----------------
__global__ __launch_bounds__(1024)
void scan_kernel(const int* __restrict__ cnt, int* __restrict__ fillptr) {
    __shared__ int psum[1024];
    const int CH = 49;
    int t = threadIdx.x;
    int base = t * CH;
    int s = 0;
    for (int i = 0; i < CH; i++) { int idx = base + i; if (idx < NN) s += cnt[idx]; }
    psum[t] = s;
    __syncthreads();
    for (int off = 1; off < 1024; off <<= 1) {
        int v = psum[t];
        int add = (t >= off) ? psum[t - off] : 0;
        __syncthreads();
        psum[t] = v + add;
        __syncthreads();
    }
    int running = (t > 0) ? psum[t - 1] : 0;
    for (int i = 0; i < CH; i++) {
        int idx = base + i;
        if (idx < NN) { fillptr[idx] = running; running += cnt[idx]; }
    }
}

// ---------------- fused: p12 (blocks 0..195) || scatter (196..977) ----------
// R12: 1024-thread blocks -> 16 waves; with 69.6KB LDS still 2 blocks/CU -> 32 waves/CU.
// Each wave owns ONE 16-row subtile (wid 0..15) -- occupancy-doubling experiment.
__global__ __launch_bounds__(1024, 8)
void p12_scatter_kernel(const void* __restrict__ hraw, const int* __restrict__ flags,
                        const short* __restrict__ we1tt, short* __restrict__ p12,
                        const void* __restrict__ ei, const void* __restrict__ dist,
                        int* __restrict__ fillptr, int4* __restrict__ epack) {
    const int tid = threadIdx.x;
    if (blockIdx.x >= P12B) {   // ---- scatter part ----
        int e = (int)(blockIdx.x - P12B) * 1024 + tid;
        if (e < EE) {
            bool i64 = flags[1] != 0;
            bool f32 = flags[0] != 0;
            int r = ldi(ei, e, i64);
            int c = ldi(ei, (long)EE + e, i64);
            int pos = atomicAdd(&fillptr[c], 1);
            int4 v;
            v.x = r; v.y = c;
            v.z = __builtin_bit_cast(int, ldw(dist, e, f32));
            v.w = 0;
            epack[pos] = v;
        }
        return;
    }
    // ---- p12 part: 256-node tile, 16 waves x 16 rows ----
    __shared__ short ht[256][136];
    const int n0 = blockIdx.x * 256;
    const bool f32 = flags[0] != 0;
    #pragma unroll
    for (int k = 0; k < 4; k++) {
        int s = tid + 1024 * k;
        int e = s >> 4, c8 = s & 15;
        int node = n0 + e; if (node >= NN) node = 0;
        if (f32) {
            const float* src = (const float*)hraw + (long)node * 128 + c8 * 8;
            float4 v0 = *(const float4*)src, v1 = *(const float4*)(src + 4);
            float vv[8] = {v0.x, v0.y, v0.z, v0.w, v1.x, v1.y, v1.z, v1.w};
            *(s8v*)&ht[e][c8 * 8] = pack8(vv);
        } else {
            uint4 v = *(const uint4*)((const short*)hraw + (long)node * 128 + c8 * 8);
            *(uint4*)&ht[e][c8 * 8] = v;
        }
    }
    __syncthreads();
    const int lane = tid & 63, wid = tid >> 6, t16 = lane & 15, q = lane >> 4, kq = q * 8;
    const int nRow = wid * 16 + t16;       // 0..255
    const int nd = n0 + nRow;

    // P1 half (We1 rows 0..127)
    f32x4 acc[8];
    #pragma unroll
    for (int mt = 0; mt < 8; mt++) acc[mt] = (f32x4){0.f, 0.f, 0.f, 0.f};
    for (int k0 = 0; k0 < 128; k0 += 32) {
        s8v bf = *(const s8v*)&ht[nRow][k0 + kq];
        #pragma unroll
        for (int mt = 0; mt < 8; mt++) {
            s8v af = *(const s8v*)(we1tt + (mt * 16 + t16) * 128 + k0 + kq);
            acc[mt] = __builtin_amdgcn_mfma_f32_16x16x32_bf16(af, bf, acc[mt], 0, 0, 0);
        }
    }
    if (nd < NN) {
        #pragma unroll
        for (int mt = 0; mt < 8; mt++) {
            int j = mt * 16 + q * 4;
            *(s4v*)(p12 + (long)nd * 256 + j) = pack4(acc[mt][0], acc[mt][1], acc[mt][2], acc[mt][3]);
        }
    }
    // P2 half (We1 rows 128..255)
    #pragma unroll
    for (int mt = 0; mt < 8; mt++) acc[mt] = (f32x4){0.f, 0.f, 0.f, 0.f};
    for (int k0 = 0; k0 < 128; k0 += 32) {
        s8v bf = *(const s8v*)&ht[nRow][k0 + kq];
        #pragma unroll
        for (int mt = 0; mt < 8; mt++) {
            s8v af = *(const s8v*)(we1tt + (128 + mt * 16 + t16) * 128 + k0 + kq);
            acc[mt] = __builtin_amdgcn_mfma_f32_16x16x32_bf16(af, bf, acc[mt], 0, 0, 0);
        }
    }
    if (nd < NN) {
        #pragma unroll
        for (int mt = 0; mt < 8; mt++) {
            int j = mt * 16 + q * 4;
            *(s4v*)(p12 + (long)nd * 256 + 128 + j) = pack4(acc[mt][0], acc[mt][1], acc[mt][2], acc[mt][3]);
        }
    }
}

// ---------------- fused edge kernel ----------------
// R12: 1024 threads / 16 waves per 256-edge tile; LDS 79KB -> 2 blocks/CU -> 32 waves/CU
// (was 16). Pure occupancy experiment: per-edge work identical to R11; each wave owns
// one 16-row subtile. VGPR ~64 << 256 cap (bounds(1024,8)) -- no spill risk.
__global__ __launch_bounds__(1024, 8)
void edge_kernel(const short* __restrict__ p12,
                 const void* __restrict__ x,
                 const int4* __restrict__ epack,
                 const int* __restrict__ flags,
                 const short* __restrict__ we2t, const short* __restrict__ wc1t,
                 const float* __restrict__ biasbuf,
                 float* __restrict__ aggMsg, float* __restrict__ aggCoord) {
    __shared__ short msgbuf[ETILE][136];
    __shared__ float s_rel[ETILE][3];
    __shared__ float s_cvec[ETILE][3];
    __shared__ int   s_col[ETILE];
    __shared__ float s_be2[128], s_wa[128], s_bc1[128], s_wc2[128];
    __shared__ float s_ba;

    const int tid = threadIdx.x;
    const int e0 = blockIdx.x * ETILE;
    const bool f32 = flags[0] != 0;

    const int jb = (tid & 15) * 8;
    float wv[8], bv[8];
    *(float4*)&wv[0] = *(const float4*)(biasbuf + 1280 + jb);
    *(float4*)&wv[4] = *(const float4*)(biasbuf + 1280 + jb + 4);
    *(float4*)&bv[0] = *(const float4*)(biasbuf + jb);
    *(float4*)&bv[4] = *(const float4*)(biasbuf + jb + 4);

    // staging: msg1 = silu(P1[row] + P2[col] + dist*w256 + be1); 4096 chunks / 1024 thr
    #pragma unroll
    for (int k = 0; k < 4; k++) {
        int e = (tid >> 4) + 64 * k;
        int4 rc = epack[e0 + e];
        float de = __builtin_bit_cast(float, rc.z);
        s8v a = *(const s8v*)(p12 + ((long)rc.x << 8) + jb);
        s8v b = *(const s8v*)(p12 + ((long)rc.y << 8) + 128 + jb);
        float vv[8];
        #pragma unroll
        for (int i = 0; i < 8; i++)
            vv[i] = fsilu(b2f(a[i]) + b2f(b[i]) + de * wv[i] + bv[i]);
        *(s8v*)&msgbuf[e][jb] = pack8(vv);
    }

    if (tid < ETILE) {
        int4 rc = epack[e0 + tid];
        s_col[tid] = rc.y;
        #pragma unroll
        for (int i = 0; i < 3; i++)
            s_rel[tid][i] = ldw(x, (long)rc.x * 3 + i, f32) - ldw(x, (long)rc.y * 3 + i, f32);
    }
    if (tid < 128) {
        s_be2[tid] = biasbuf[128 + tid];
        s_wa[tid]  = biasbuf[384 + tid];
        s_bc1[tid] = biasbuf[256 + tid];
        s_wc2[tid] = biasbuf[512 + tid];
    }
    if (tid == 0) s_ba = biasbuf[640];
    __syncthreads();

    const int lane = tid & 63;
    const int wid  = tid >> 6;              // 0..15
    const int t16 = lane & 15, q = lane >> 4;
    const int eRow = wid * 16 + t16;        // 0..255
    const int kq = q * 8;

    // ---- GEMM2': msg = We2T . msg1 + be2 ----
    f32x4 acc2[8];
    #pragma unroll
    for (int mt = 0; mt < 8; mt++) acc2[mt] = (f32x4){0.f, 0.f, 0.f, 0.f};
    for (int k0 = 0; k0 < 128; k0 += 32) {
        s8v bf = *(const s8v*)&msgbuf[eRow][k0 + kq];
        #pragma unroll
        for (int mt = 0; mt < 8; mt++) {
            s8v af = *(const s8v*)(we2t + (mt * 16 + t16) * 128 + k0 + kq);
            acc2[mt] = __builtin_amdgcn_mfma_f32_16x16x32_bf16(af, bf, acc2[mt], 0, 0, 0);
        }
    }
    float part = 0.f;
    #pragma unroll
    for (int mt = 0; mt < 8; mt++) {
        #pragma unroll
        for (int r = 0; r < 4; r++) {
            int j = mt * 16 + q * 4 + r;
            acc2[mt][r] += s_be2[j];
            part += acc2[mt][r] * s_wa[j];
        }
    }
    part += __shfl_xor(part, 16);
    part += __shfl_xor(part, 32);
    float attn = 1.f / (1.f + __expf(-(part + s_ba)));
    #pragma unroll
    for (int mt = 0; mt < 8; mt++) {
        int jbw = mt * 16 + q * 4;
        *(s4v*)&msgbuf[eRow][jbw] = pack4(acc2[mt][0] * attn, acc2[mt][1] * attn,
                                          acc2[mt][2] * attn, acc2[mt][3] * attn);
    }

    // ---- GEMM3': coord_w = silu(Wc1T . msg + bc1) . Wc2 ----
    f32x4 acc3[8];
    #pragma unroll
    for (int mt = 0; mt < 8; mt++) acc3[mt] = (f32x4){0.f, 0.f, 0.f, 0.f};
    for (int k0 = 0; k0 < 128; k0 += 32) {
        s8v bf = *(const s8v*)&msgbuf[eRow][k0 + kq];
        #pragma unroll
        for (int mt = 0; mt < 8; mt++) {
            s8v af = *(const s8v*)(wc1t + (mt * 16 + t16) * 128 + k0 + kq);
            acc3[mt] = __builtin_amdgcn_mfma_f32_16x16x32_bf16(af, bf, acc3[mt], 0, 0, 0);
        }
    }
    float part2 = 0.f;
    #pragma unroll
    for (int mt = 0; mt < 8; mt++) {
        #pragma unroll
        for (int r = 0; r < 4; r++) {
            int j = mt * 16 + q * 4 + r;
            part2 += fsilu(acc3[mt][r] + s_bc1[j]) * s_wc2[j];
        }
    }
    part2 += __shfl_xor(part2, 16);
    part2 += __shfl_xor(part2, 32);
    if (q == 0) {
        #pragma unroll
        for (int i = 0; i < 3; i++) s_cvec[eRow][i] = s_rel[eRow][i] * part2;
    }
    __syncthreads();

    // ---- segmented reduce over sorted cols: 8 groups of 32 edges, register-batched ----
    {
        int j = tid & 127;
        int eh = (tid >> 7) * 32;        // groups 0..7
        int runcol = s_col[eh];
        float racc = 0.f;
        #pragma unroll
        for (int half = 0; half < 2; half++) {
            float mv[16]; int cv[16];
            #pragma unroll
            for (int t = 0; t < 16; t++) {
                int e = eh + half * 16 + t;
                mv[t] = b2f(msgbuf[e][j]);
                cv[t] = s_col[e];
            }
            #pragma unroll
            for (int t = 0; t < 16; t++) {
                if (cv[t] != runcol) {
                    unsafeAtomicAdd(&aggMsg[(long)runcol * 128 + j], racc);
                    runcol = cv[t]; racc = 0.f;
                }
                racc += mv[t];
            }
        }
        unsafeAtomicAdd(&aggMsg[(long)runcol * 128 + j], racc);
    }
    if (tid < 96) {
        int i = tid % 3, sl = tid / 3;   // 32 slices of 8 edges
        int eh = sl * 8;
        int runcol = s_col[eh];
        float racc = 0.f;
        for (int e = eh; e < eh + 8; e++) {
            int c = s_col[e];
            if (c != runcol) {
                unsafeAtomicAdd(&aggCoord[(long)runcol * 3 + i], racc);
                runcol = c; racc = 0.f;
            }
            racc += s_cvec[e][i];
        }
        unsafeAtomicAdd(&aggCoord[(long)runcol * 3 + i], racc);
    }
}

// ---------------- fused: node (blocks 0..390) || xnew (391..683) ----------------
__global__ __launch_bounds__(512, 4)
void node_xnew_kernel(const void* __restrict__ hraw, const float* __restrict__ aggMsg,
                      const short* __restrict__ wn1t, const short* __restrict__ wn2t,
                      const float* __restrict__ biasbuf, const int* __restrict__ flags,
                      const void* __restrict__ x, const float* __restrict__ aggCoord,
                      void* __restrict__ out) {
    const int tid = threadIdx.x;
    const bool outf32 = flags[0] != 0;
    if (blockIdx.x >= NODEB) {   // ---- xnew part ----
        int i = (int)(blockIdx.x - NODEB) * 512 + tid;
        if (i < NN * 3) {
            float v = ldw(x, i, outf32) + aggCoord[i];
            if (outf32) ((float*)out)[(long)NN * 128 + i] = v;
            else        ((short*)out)[(long)NN * 128 + i] = bf16r(v);
        }
        return;
    }
    __shared__ short feat[128][264];
    __shared__ float s_bn1[128], s_bn2[128], s_g[128], s_b[128];
    const int n0 = blockIdx.x * 128;

    if (tid < 128) {
        s_bn1[tid] = biasbuf[768 + tid];
        s_bn2[tid] = biasbuf[896 + tid];
        s_g[tid]   = biasbuf[1024 + tid];
        s_b[tid]   = biasbuf[1152 + tid];
    }
    #pragma unroll
    for (int k = 0; k < 4; k++) {
        int s = tid + 512 * k;
        int e = s >> 4, c8 = s & 15;
        int node = n0 + e; if (node >= NN) node = 0;
        if (outf32) {
            const float* src = (const float*)hraw + (long)node * 128 + c8 * 8;
            float4 v0 = *(const float4*)src, v1 = *(const float4*)(src + 4);
            float vv[8] = {v0.x, v0.y, v0.z, v0.w, v1.x, v1.y, v1.z, v1.w};
            *(s8v*)&feat[e][c8 * 8] = pack8(vv);
        } else {
            uint4 v = *(const uint4*)((const short*)hraw + (long)node * 128 + c8 * 8);
            *(uint4*)&feat[e][c8 * 8] = v;
        }
    }
    #pragma unroll
    for (int k = 0; k < 8; k++) {
        int s = tid + 512 * k;
        int e = s >> 5, k4 = s & 31;
        int node = n0 + e; if (node >= NN) node = 0;
        float4 v = ((const float4*)(aggMsg + (long)node * 128))[k4];
        *(s4v*)&feat[e][128 + k4 * 4] = pack4(v.x, v.y, v.z, v.w);
    }
    __syncthreads();

    const int lane = tid & 63;
    const int wid  = tid >> 6;           // 0..7
    const int t16 = lane & 15, q = lane >> 4;
    const int eRow = wid * 16 + t16;     // 0..127
    const int kq = q * 8;

    f32x4 acc[8];
    #pragma unroll
    for (int mt = 0; mt < 8; mt++) acc[mt] = (f32x4){0.f, 0.f, 0.f, 0.f};
    for (int k0 = 0; k0 < 256; k0 += 32) {
        s8v bf = *(const s8v*)&feat[eRow][k0 + kq];
        #pragma unroll
        for (int mt = 0; mt < 8; mt++) {
            s8v af = *(const s8v*)(wn1t + (mt * 16 + t16) * 256 + k0 + kq);
            acc[mt] = __builtin_amdgcn_mfma_f32_16x16x32_bf16(af, bf, acc[mt], 0, 0, 0);
        }
    }
    s4v hres[8];
    #pragma unroll
    for (int mt = 0; mt < 8; mt++) hres[mt] = *(const s4v*)&feat[eRow][mt * 16 + q * 4];
    #pragma unroll
    for (int mt = 0; mt < 8; mt++) {
        int jb = mt * 16 + q * 4;
        *(s4v*)&feat[eRow][jb] = pack4(fsilu(acc[mt][0] + s_bn1[jb + 0]),
                                       fsilu(acc[mt][1] + s_bn1[jb + 1]),
                                       fsilu(acc[mt][2] + s_bn1[jb + 2]),
                                       fsilu(acc[mt][3] + s_bn1[jb + 3]));
    }

    f32x4 acc2[8];
    #pragma unroll
    for (int mt = 0; mt < 8; mt++) acc2[mt] = (f32x4){0.f, 0.f, 0.f, 0.f};
    for (int k0 = 0; k0 < 128; k0 += 32) {
        s8v bf = *(const s8v*)&feat[eRow][k0 + kq];
        #pragma unroll
        for (int mt = 0; mt < 8; mt++) {
            s8v af = *(const s8v*)(wn2t + (mt * 16 + t16) * 128 + k0 + kq);
            acc2[mt] = __builtin_amdgcn_mfma_f32_16x16x32_bf16(af, bf, acc2[mt], 0, 0, 0);
        }
    }
    float zsum = 0.f, zsq = 0.f;
    #pragma unroll
    for (int mt = 0; mt < 8; mt++) {
        #pragma unroll
        for (int r = 0; r < 4; r++) {
            int j = mt * 16 + q * 4 + r;
            float z = b2f(hres[mt][r]) + acc2[mt][r] + s_bn2[j];
            acc2[mt][r] = z;
            zsum += z;
            zsq += z * z;
        }
    }
    zsum += __shfl_xor(zsum, 16); zsum += __shfl_xor(zsum, 32);
    zsq  += __shfl_xor(zsq, 16);  zsq  += __shfl_xor(zsq, 32);
    float mu = zsum * (1.f / 128.f);
    float var = zsq * (1.f / 128.f) - mu * mu;
    float rstd = rsqrtf(fmaxf(var, 0.f) + 1e-5f);
    int node = n0 + eRow;
    if (node < NN) {
        if (outf32) {
            float* o = (float*)out + (long)node * 128;
            #pragma unroll
            for (int mt = 0; mt < 8; mt++) {
                int jb = mt * 16 + q * 4;
                float4 pk;
                pk.x = (acc2[mt][0] - mu) * rstd * s_g[jb + 0] + s_b[jb + 0];
                pk.y = (acc2[mt][1] - mu) * rstd * s_g[jb + 1] + s_b[jb + 1];
                pk.z = (acc2[mt][2] - mu) * rstd * s_g[jb + 2] + s_b[jb + 2];
                pk.w = (acc2[mt][3] - mu) * rstd * s_g[jb + 3] + s_b[jb + 3];
                *(float4*)&o[jb] = pk;
            }
        } else {
            short* o = (short*)out + (long)node * 128;
            #pragma unroll
            for (int mt = 0; mt < 8; mt++) {
                int jb = mt * 16 + q * 4;
                s4v pk = pack4((acc2[mt][0] - mu) * rstd * s_g[jb + 0] + s_b[jb + 0],
                               (acc2[mt][1] - mu) * rstd * s_g[jb + 1] + s_b[jb + 1],
                               (acc2[mt][2] - mu) * rstd * s_g[jb + 2] + s_b[jb + 2],
                               (acc2[mt][3] - mu) * rstd * s_g[jb + 3] + s_b[jb + 3]);
                *(s4v*)&o[jb] = pk;
            }
        }
    }
}

// ---------------- launch ----------------
extern "C" void kernel_launch(void* const* d_in, const int* in_sizes, int n_in,
                              void* d_out, int out_size, void* d_ws, size_t ws_size,
                              hipStream_t stream) {
    const void* h    = d_in[0];
    const void* x    = d_in[1];
    const void* ei   = d_in[2];
    const void* dist = d_in[3];
    const void* We1  = d_in[4];
    const void* be1  = d_in[5];
    const void* We2  = d_in[6];
    const void* be2  = d_in[7];
    const void* Wa   = d_in[8];
    const void* ba   = d_in[9];
    const void* Wn1  = d_in[10];
    const void* bn1  = d_in[11];
    const void* Wn2  = d_in[12];
    const void* bn2  = d_in[13];
    const void* Wc1  = d_in[14];
    const void* bc1  = d_in[15];
    const void* Wc2  = d_in[16];
    const void* gmma = d_in[17];
    const void* beta = d_in[18];

    char* ws = (char*)d_ws;
    int*   flags   = (int*)ws;                          // @0
    short* we1tt   = (short*)(ws + 1024);               // 65536
    short* we2t    = (short*)(ws + 66560);              // 32768
    short* wc1t    = (short*)(ws + 99328);              // 32768
    short* wn1t    = (short*)(ws + 132096);             // 65536
    short* wn2t    = (short*)(ws + 197632);             // 32768
    float* biasbuf = (float*)(ws + 230400);             // 5632
    short* p12     = (short*)(ws + 236544);             // 25.6 MB -> 25836544
    float* aggMsg  = (float*)(ws + 25836544);           // 25.6 MB -> 51436544
    float* aggCoord= (float*)(ws + 51436544);           // 0.6 MB  -> 52036544
    int*   cnt     = (int*)(ws + 52036544);             // 0.2 MB  -> 52236544 (zeroed by memset)
    int*   fillptr = (int*)(ws + 52236544);             // 0.2 MB  -> 52436544
    // d_out scratch (consumed by edge_kernel BEFORE node/xnew overwrite d_out):
    // epack int4[800000] = 12.8MB (<= 13.1MB bf16-out lower bound)
    int4*  epack   = (int4*)d_out;

    // memset covers aggMsg + aggCoord + cnt (contiguous: NN*128 + NN*3 + NN floats)
    hipMemsetAsync(aggMsg, 0, (size_t)(NN * 128 + NN * 3 + NN) * sizeof(float), stream);
    detect_kernel<<<1, 256, 0, stream>>>((const unsigned*)h, (const unsigned*)ei, flags);
    prep_hist_kernel<<<PREPB + HISTB, 256, 0, stream>>>(We1, We2, Wc1, Wn1, Wn2,
                                                        be1, be2, bc1, Wa, ba, Wc2,
                                                        bn1, bn2, gmma, beta, ei, flags,
                                                        we1tt, we2t, wc1t, wn1t, wn2t,
                                                        biasbuf, cnt);
    scan_kernel<<<1, 1024, 0, stream>>>(cnt, fillptr);
    p12_scatter_kernel<<<P12B + SCATB, 1024, 0, stream>>>(h, flags, we1tt, p12,
                                                          ei, dist, fillptr, epack);
    edge_kernel<<<EE / ETILE, 1024, 0, stream>>>(p12, x, epack, flags,
                                                 we2t, wc1t, biasbuf, aggMsg, aggCoord);
    node_xnew_kernel<<<NODEB + XNEWB, 512, 0, stream>>>(h, aggMsg, wn1t, wn2t, biasbuf,
                                                        flags, x, aggCoord, d_out);
}

// Round 8
// 782.046 us; speedup vs baseline: 1.1757x; 1.1757x over previous
//
#include <hip/hip_runtime.h>
#include <hip/hip_bf16.h>
#include <stdint.h>

// ---------------- constants ----------------
#define NN 50000
#define EE 800000
#define HD 128
#define ETILE 128    // R13: 128-edge tile -> LDS ~39KB -> 4 blocks/CU -> 32 waves/CU
#define PREPB 769
#define HISTB 3125   // (EE+255)/256
#define P12B  196    // (NN+255)/256
#define SCATB 1563   // (EE+511)/512
#define NODEB 391    // (NN+127)/128
#define XNEWB 293    // (NN*3+511)/512

typedef __attribute__((ext_vector_type(8))) short s8v;   // 8 bf16 (4 VGPRs) mfma A/B frag
typedef __attribute__((ext_vector_type(4))) short s4v;   // 4 bf16 (8B)
typedef __attribute__((ext_vector_type(4))) float f32x4; // mfma C/D frag

__device__ inline float b2f(short s) {
    unsigned u = ((unsigned)(unsigned short)s) << 16;
    return __builtin_bit_cast(float, u);
}
__device__ inline short bf16r(float f) {
    unsigned u = __builtin_bit_cast(unsigned, f);
    unsigned r = (u + 0x7fffu + ((u >> 16) & 1u)) >> 16;
    return (short)r;
}
__device__ inline s4v pack4(float a, float b, float c, float d) {
    union { __hip_bfloat162 h2[2]; s4v v; } u;
    u.h2[0] = __float22bfloat162_rn(make_float2(a, b));
    u.h2[1] = __float22bfloat162_rn(make_float2(c, d));
    return u.v;
}
__device__ inline s8v pack8(const float* v) {
    union { __hip_bfloat162 h2[4]; s8v v8; } u;
    #pragma unroll
    for (int i = 0; i < 4; i++) u.h2[i] = __float22bfloat162_rn(make_float2(v[2*i], v[2*i+1]));
    return u.v8;
}
__device__ inline float fsilu(float v) { return v / (1.f + __expf(-v)); }

__device__ inline float ldw(const void* p, long i, bool f32) {
    return f32 ? ((const float*)p)[i] : b2f(((const short*)p)[i]);
}
__device__ inline short ldb(const void* p, long i, bool f32) {
    return f32 ? bf16r(((const float*)p)[i]) : ((const short*)p)[i];
}
__device__ inline int ldi(const void* p, long i, bool i64) {
    return i64 ? (int)((const long long*)p)[i] : ((const int*)p)[i];
}

// ---------------- dtype detection ----------------
__global__ void detect_kernel(const unsigned* __restrict__ h_raw,
                              const unsigned* __restrict__ ei_raw, int* flags) {
    __shared__ int cnt_f32, cnt_nz;
    int t = threadIdx.x;
    if (t == 0) { cnt_f32 = 0; cnt_nz = 0; }
    __syncthreads();
    unsigned u = h_raw[t];
    unsigned ex = (u >> 23) & 0xFFu;
    int isf = (ex >= 100u && ex <= 150u) ? 1 : 0;
    unsigned w = ei_raw[2 * t + 1];
    int nz = (w != 0u) ? 1 : 0;
    atomicAdd(&cnt_f32, isf);
    atomicAdd(&cnt_nz, nz);
    __syncthreads();
    if (t == 0) {
        flags[0] = (cnt_f32 >= 128) ? 1 : 0;
        flags[1] = (cnt_nz < 8) ? 1 : 0;
    }
}

// ---------------- fused: prep_weights (blocks 0..768) || hist (blocks 769..3893) ----------
__global__ __launch_bounds__(256)
void prep_hist_kernel(const void* we1, const void* we2, const void* wc1,
                      const void* wn1, const void* wn2,
                      const void* be1, const void* be2, const void* bc1,
                      const void* wa, const void* ba, const void* wc2,
                      const void* bn1, const void* bn2,
                      const void* gmma, const void* beta,
                      const void* __restrict__ ei,
                      const int* __restrict__ flags,
                      short* __restrict__ we1tt, short* __restrict__ we2t,
                      short* __restrict__ wc1t, short* __restrict__ wn1t,
                      short* __restrict__ wn2t, float* __restrict__ biasbuf,
                      int* __restrict__ cnt) {
    bool f32 = flags[0] != 0;
    int b = blockIdx.x, t = threadIdx.x;
    if (b >= PREPB) {   // ---- hist part ----
        int e = (b - PREPB) * 256 + t;
        if (e < EE) atomicAdd(&cnt[ldi(ei, (long)EE + e, flags[1] != 0)], 1);
        return;
    }
    if (b < 256) {
        if (t < 128) we1tt[b * 128 + t] = ldb(we1, (long)((b < 128 ? t : t + 128)) * 128 + (b & 127), f32);
    } else if (b < 384) {
        int j = b - 256; if (t < 128) we2t[j * 128 + t] = ldb(we2, t * 128 + j, f32);
    } else if (b < 512) {
        int j = b - 384; if (t < 128) wc1t[j * 128 + t] = ldb(wc1, t * 128 + j, f32);
    } else if (b < 640) {
        int j = b - 512; wn1t[j * 256 + t] = ldb(wn1, t * 128 + j, f32);   // j in [0,128)
    } else if (b < 768) {
        int j = b - 640; if (t < 128) wn2t[j * 128 + t] = ldb(wn2, t * 128 + j, f32);
    } else if (t < 128) {
        biasbuf[t]         = ldw(be1, t, f32);
        biasbuf[128 + t]   = ldw(be2, t, f32);
        biasbuf[256 + t]   = ldw(bc1, t, f32);
        biasbuf[384 + t]   = ldw(wa, t, f32);
        biasbuf[512 + t]   = ldw(wc2, t, f32);
        biasbuf[768 + t]   = ldw(bn1, t, f32);
        biasbuf[896 + t]   = ldw(bn2, t, f32);
        biasbuf[1024 + t]  = ldw(gmma, t, f32);
        biasbuf[1152 + t]  = ldw(beta, t, f32);
        biasbuf[1280 + t]  = ldw(we1, 256 * 128 + t, f32);   // We1 dist row
        if (t == 0) biasbuf[640] = ldw(ba, 0, f32);
    }
}

// ---------------- exclusive scan of cnt[50000] -> fillptr ----------------
__global__ __launch_bounds__(1024)
void scan_kernel(const int* __restrict__ cnt, int* __restrict__ fillptr) {
    __shared__ int psum[1024];
    const int CH = 49;
    int t = threadIdx.x;
    int base = t * CH;
    int s = 0;
    for (int i = 0; i < CH; i++) { int idx = base + i; if (idx < NN) s += cnt[idx]; }
    psum[t] = s;
    __syncthreads();
    for (int off = 1; off < 1024; off <<= 1) {
        int v = psum[t];
        int add = (t >= off) ? psum[t - off] : 0;
        __syncthreads();
        psum[t] = v + add;
        __syncthreads();
    }
    int running = (t > 0) ? psum[t - 1] : 0;
    for (int i = 0; i < CH; i++) {
        int idx = base + i;
        if (idx < NN) { fillptr[idx] = running; running += cnt[idx]; }
    }
}

// ---------------- fused: p12 (blocks 0..195) || scatter (196..1758) ----------
// R13: reverted to R11's proven 512-thread / bounds(512,4) config (R12's 1024-thr
// variant spilled: bounds(1024,8) caps VGPR at 64 which this code can't meet).
__global__ __launch_bounds__(512, 4)
void p12_scatter_kernel(const void* __restrict__ hraw, const int* __restrict__ flags,
                        const short* __restrict__ we1tt, short* __restrict__ p12,
                        const void* __restrict__ ei, const void* __restrict__ dist,
                        int* __restrict__ fillptr, int4* __restrict__ epack) {
    const int tid = threadIdx.x;
    if (blockIdx.x >= P12B) {   // ---- scatter part ----
        int e = (int)(blockIdx.x - P12B) * 512 + tid;
        if (e < EE) {
            bool i64 = flags[1] != 0;
            bool f32 = flags[0] != 0;
            int r = ldi(ei, e, i64);
            int c = ldi(ei, (long)EE + e, i64);
            int pos = atomicAdd(&fillptr[c], 1);
            int4 v;
            v.x = r; v.y = c;
            v.z = __builtin_bit_cast(int, ldw(dist, e, f32));
            v.w = 0;
            epack[pos] = v;
        }
        return;
    }
    // ---- p12 part: 256-node tile, 8 waves x dual 16-row subtiles ----
    __shared__ short ht[256][136];
    const int n0 = blockIdx.x * 256;
    const bool f32 = flags[0] != 0;
    #pragma unroll
    for (int k = 0; k < 8; k++) {
        int s = tid + 512 * k;
        int e = s >> 4, c8 = s & 15;
        int node = n0 + e; if (node >= NN) node = 0;
        if (f32) {
            const float* src = (const float*)hraw + (long)node * 128 + c8 * 8;
            float4 v0 = *(const float4*)src, v1 = *(const float4*)(src + 4);
            float vv[8] = {v0.x, v0.y, v0.z, v0.w, v1.x, v1.y, v1.z, v1.w};
            *(s8v*)&ht[e][c8 * 8] = pack8(vv);
        } else {
            uint4 v = *(const uint4*)((const short*)hraw + (long)node * 128 + c8 * 8);
            *(uint4*)&ht[e][c8 * 8] = v;
        }
    }
    __syncthreads();
    const int lane = tid & 63, wid = tid >> 6, t16 = lane & 15, q = lane >> 4, kq = q * 8;
    const int rA = wid * 32 + t16, rB = rA + 16;
    const int ndA = n0 + rA, ndB = n0 + rB;

    // P1 half (We1 rows 0..127)
    f32x4 aA[8], aB[8];
    #pragma unroll
    for (int mt = 0; mt < 8; mt++) { aA[mt] = (f32x4){0.f,0.f,0.f,0.f}; aB[mt] = (f32x4){0.f,0.f,0.f,0.f}; }
    for (int k0 = 0; k0 < 128; k0 += 32) {
        s8v bfA = *(const s8v*)&ht[rA][k0 + kq];
        s8v bfB = *(const s8v*)&ht[rB][k0 + kq];
        #pragma unroll
        for (int mt = 0; mt < 8; mt++) {
            s8v af = *(const s8v*)(we1tt + (mt * 16 + t16) * 128 + k0 + kq);
            aA[mt] = __builtin_amdgcn_mfma_f32_16x16x32_bf16(af, bfA, aA[mt], 0, 0, 0);
            aB[mt] = __builtin_amdgcn_mfma_f32_16x16x32_bf16(af, bfB, aB[mt], 0, 0, 0);
        }
    }
    if (ndA < NN) {
        #pragma unroll
        for (int mt = 0; mt < 8; mt++) {
            int j = mt * 16 + q * 4;
            *(s4v*)(p12 + (long)ndA * 256 + j) = pack4(aA[mt][0], aA[mt][1], aA[mt][2], aA[mt][3]);
        }
    }
    if (ndB < NN) {
        #pragma unroll
        for (int mt = 0; mt < 8; mt++) {
            int j = mt * 16 + q * 4;
            *(s4v*)(p12 + (long)ndB * 256 + j) = pack4(aB[mt][0], aB[mt][1], aB[mt][2], aB[mt][3]);
        }
    }

    // P2 half (We1 rows 128..255)
    #pragma unroll
    for (int mt = 0; mt < 8; mt++) { aA[mt] = (f32x4){0.f,0.f,0.f,0.f}; aB[mt] = (f32x4){0.f,0.f,0.f,0.f}; }
    for (int k0 = 0; k0 < 128; k0 += 32) {
        s8v bfA = *(const s8v*)&ht[rA][k0 + kq];
        s8v bfB = *(const s8v*)&ht[rB][k0 + kq];
        #pragma unroll
        for (int mt = 0; mt < 8; mt++) {
            s8v af = *(const s8v*)(we1tt + (128 + mt * 16 + t16) * 128 + k0 + kq);
            aA[mt] = __builtin_amdgcn_mfma_f32_16x16x32_bf16(af, bfA, aA[mt], 0, 0, 0);
            aB[mt] = __builtin_amdgcn_mfma_f32_16x16x32_bf16(af, bfB, aB[mt], 0, 0, 0);
        }
    }
    if (ndA < NN) {
        #pragma unroll
        for (int mt = 0; mt < 8; mt++) {
            int j = mt * 16 + q * 4;
            *(s4v*)(p12 + (long)ndA * 256 + 128 + j) = pack4(aA[mt][0], aA[mt][1], aA[mt][2], aA[mt][3]);
        }
    }
    if (ndB < NN) {
        #pragma unroll
        for (int mt = 0; mt < 8; mt++) {
            int j = mt * 16 + q * 4;
            *(s4v*)(p12 + (long)ndB * 256 + 128 + j) = pack4(aB[mt][0], aB[mt][1], aB[mt][2], aB[mt][3]);
        }
    }
}

// ---------------- fused edge kernel ----------------
// R13: 128-edge tile, 512 threads, bounds(512,4) (proven spill-free cap of 128).
// LDS ~39KB -> 4 blocks/CU; per-wave VGPR use ~48-64 -> HW allows 8 waves/SIMD ->
// 32 waves/CU (R11 had 16). Occupancy-doubling without touching the register cap
// (R12's 1024-thr route forced cap 64 -> spilled). s_cvec merged into s_rel to
// stay under 40KB/block.
__global__ __launch_bounds__(512, 4)
void edge_kernel(const short* __restrict__ p12,
                 const void* __restrict__ x,
                 const int4* __restrict__ epack,
                 const int* __restrict__ flags,
                 const short* __restrict__ we2t, const short* __restrict__ wc1t,
                 const float* __restrict__ biasbuf,
                 float* __restrict__ aggMsg, float* __restrict__ aggCoord) {
    __shared__ short msgbuf[ETILE][136];
    __shared__ float s_rel[ETILE][3];     // rel_pos, overwritten in place by cvec
    __shared__ int   s_col[ETILE];
    __shared__ float s_be2[128], s_wa[128], s_bc1[128], s_wc2[128];
    __shared__ float s_ba;

    const int tid = threadIdx.x;
    const int e0 = blockIdx.x * ETILE;
    const bool f32 = flags[0] != 0;

    const int jb = (tid & 15) * 8;
    float wv[8], bv[8];
    *(float4*)&wv[0] = *(const float4*)(biasbuf + 1280 + jb);
    *(float4*)&wv[4] = *(const float4*)(biasbuf + 1280 + jb + 4);
    *(float4*)&bv[0] = *(const float4*)(biasbuf + jb);
    *(float4*)&bv[4] = *(const float4*)(biasbuf + jb + 4);

    // staging: msg1 = silu(P1[row] + P2[col] + dist*w256 + be1); 2048 chunks / 512 thr
    #pragma unroll
    for (int k = 0; k < 4; k++) {
        int e = (tid >> 4) + 32 * k;
        int4 rc = epack[e0 + e];
        float de = __builtin_bit_cast(float, rc.z);
        s8v a = *(const s8v*)(p12 + ((long)rc.x << 8) + jb);
        s8v b = *(const s8v*)(p12 + ((long)rc.y << 8) + 128 + jb);
        float vv[8];
        #pragma unroll
        for (int i = 0; i < 8; i++)
            vv[i] = fsilu(b2f(a[i]) + b2f(b[i]) + de * wv[i] + bv[i]);
        *(s8v*)&msgbuf[e][jb] = pack8(vv);
    }

    if (tid < ETILE) {
        int4 rc = epack[e0 + tid];
        s_col[tid] = rc.y;
        #pragma unroll
        for (int i = 0; i < 3; i++)
            s_rel[tid][i] = ldw(x, (long)rc.x * 3 + i, f32) - ldw(x, (long)rc.y * 3 + i, f32);
    }
    if (tid < 128) {
        s_be2[tid] = biasbuf[128 + tid];
        s_wa[tid]  = biasbuf[384 + tid];
        s_bc1[tid] = biasbuf[256 + tid];
        s_wc2[tid] = biasbuf[512 + tid];
    }
    if (tid == 0) s_ba = biasbuf[640];
    __syncthreads();

    const int lane = tid & 63;
    const int wid  = tid >> 6;              // 0..7
    const int t16 = lane & 15, q = lane >> 4;
    const int eRow = wid * 16 + t16;        // 0..127
    const int kq = q * 8;

    // ---- GEMM2': msg = We2T . msg1 + be2 ----
    f32x4 acc2[8];
    #pragma unroll
    for (int mt = 0; mt < 8; mt++) acc2[mt] = (f32x4){0.f, 0.f, 0.f, 0.f};
    for (int k0 = 0; k0 < 128; k0 += 32) {
        s8v bf = *(const s8v*)&msgbuf[eRow][k0 + kq];
        #pragma unroll
        for (int mt = 0; mt < 8; mt++) {
            s8v af = *(const s8v*)(we2t + (mt * 16 + t16) * 128 + k0 + kq);
            acc2[mt] = __builtin_amdgcn_mfma_f32_16x16x32_bf16(af, bf, acc2[mt], 0, 0, 0);
        }
    }
    float part = 0.f;
    #pragma unroll
    for (int mt = 0; mt < 8; mt++) {
        #pragma unroll
        for (int r = 0; r < 4; r++) {
            int j = mt * 16 + q * 4 + r;
            acc2[mt][r] += s_be2[j];
            part += acc2[mt][r] * s_wa[j];
        }
    }
    part += __shfl_xor(part, 16);
    part += __shfl_xor(part, 32);
    float attn = 1.f / (1.f + __expf(-(part + s_ba)));
    #pragma unroll
    for (int mt = 0; mt < 8; mt++) {
        int jbw = mt * 16 + q * 4;
        *(s4v*)&msgbuf[eRow][jbw] = pack4(acc2[mt][0] * attn, acc2[mt][1] * attn,
                                          acc2[mt][2] * attn, acc2[mt][3] * attn);
    }

    // ---- GEMM3': coord_w = silu(Wc1T . msg + bc1) . Wc2 ----
    f32x4 acc3[8];
    #pragma unroll
    for (int mt = 0; mt < 8; mt++) acc3[mt] = (f32x4){0.f, 0.f, 0.f, 0.f};
    for (int k0 = 0; k0 < 128; k0 += 32) {
        s8v bf = *(const s8v*)&msgbuf[eRow][k0 + kq];
        #pragma unroll
        for (int mt = 0; mt < 8; mt++) {
            s8v af = *(const s8v*)(wc1t + (mt * 16 + t16) * 128 + k0 + kq);
            acc3[mt] = __builtin_amdgcn_mfma_f32_16x16x32_bf16(af, bf, acc3[mt], 0, 0, 0);
        }
    }
    float part2 = 0.f;
    #pragma unroll
    for (int mt = 0; mt < 8; mt++) {
        #pragma unroll
        for (int r = 0; r < 4; r++) {
            int j = mt * 16 + q * 4 + r;
            part2 += fsilu(acc3[mt][r] + s_bc1[j]) * s_wc2[j];
        }
    }
    part2 += __shfl_xor(part2, 16);
    part2 += __shfl_xor(part2, 32);
    if (q == 0) {
        #pragma unroll
        for (int i = 0; i < 3; i++) s_rel[eRow][i] = s_rel[eRow][i] * part2;  // cvec in place
    }
    __syncthreads();

    // ---- segmented reduce over sorted cols: 4 groups of 32 edges, register-batched ----
    {
        int j = tid & 127;
        int eh = (tid >> 7) * 32;        // groups 0..3
        int runcol = s_col[eh];
        float racc = 0.f;
        #pragma unroll
        for (int half = 0; half < 2; half++) {
            float mv[16]; int cv[16];
            #pragma unroll
            for (int t = 0; t < 16; t++) {
                int e = eh + half * 16 + t;
                mv[t] = b2f(msgbuf[e][j]);
                cv[t] = s_col[e];
            }
            #pragma unroll
            for (int t = 0; t < 16; t++) {
                if (cv[t] != runcol) {
                    unsafeAtomicAdd(&aggMsg[(long)runcol * 128 + j], racc);
                    runcol = cv[t]; racc = 0.f;
                }
                racc += mv[t];
            }
        }
        unsafeAtomicAdd(&aggMsg[(long)runcol * 128 + j], racc);
    }
    if (tid < 48) {
        int i = tid % 3, sl = tid / 3;   // 16 slices of 8 edges
        int eh = sl * 8;
        int runcol = s_col[eh];
        float racc = 0.f;
        for (int e = eh; e < eh + 8; e++) {
            int c = s_col[e];
            if (c != runcol) {
                unsafeAtomicAdd(&aggCoord[(long)runcol * 3 + i], racc);
                runcol = c; racc = 0.f;
            }
            racc += s_rel[e][i];         // cvec (written in place)
        }
        unsafeAtomicAdd(&aggCoord[(long)runcol * 3 + i], racc);
    }
}

// ---------------- fused: node (blocks 0..390) || xnew (391..683) ----------------
__global__ __launch_bounds__(512, 4)
void node_xnew_kernel(const void* __restrict__ hraw, const float* __restrict__ aggMsg,
                      const short* __restrict__ wn1t, const short* __restrict__ wn2t,
                      const float* __restrict__ biasbuf, const int* __restrict__ flags,
                      const void* __restrict__ x, const float* __restrict__ aggCoord,
                      void* __restrict__ out) {
    const int tid = threadIdx.x;
    const bool outf32 = flags[0] != 0;
    if (blockIdx.x >= NODEB) {   // ---- xnew part ----
        int i = (int)(blockIdx.x - NODEB) * 512 + tid;
        if (i < NN * 3) {
            float v = ldw(x, i, outf32) + aggCoord[i];
            if (outf32) ((float*)out)[(long)NN * 128 + i] = v;
            else        ((short*)out)[(long)NN * 128 + i] = bf16r(v);
        }
        return;
    }
    __shared__ short feat[128][264];
    __shared__ float s_bn1[128], s_bn2[128], s_g[128], s_b[128];
    const int n0 = blockIdx.x * 128;

    if (tid < 128) {
        s_bn1[tid] = biasbuf[768 + tid];
        s_bn2[tid] = biasbuf[896 + tid];
        s_g[tid]   = biasbuf[1024 + tid];
        s_b[tid]   = biasbuf[1152 + tid];
    }
    #pragma unroll
    for (int k = 0; k < 4; k++) {
        int s = tid + 512 * k;
        int e = s >> 4, c8 = s & 15;
        int node = n0 + e; if (node >= NN) node = 0;
        if (outf32) {
            const float* src = (const float*)hraw + (long)node * 128 + c8 * 8;
            float4 v0 = *(const float4*)src, v1 = *(const float4*)(src + 4);
            float vv[8] = {v0.x, v0.y, v0.z, v0.w, v1.x, v1.y, v1.z, v1.w};
            *(s8v*)&feat[e][c8 * 8] = pack8(vv);
        } else {
            uint4 v = *(const uint4*)((const short*)hraw + (long)node * 128 + c8 * 8);
            *(uint4*)&feat[e][c8 * 8] = v;
        }
    }
    #pragma unroll
    for (int k = 0; k < 8; k++) {
        int s = tid + 512 * k;
        int e = s >> 5, k4 = s & 31;
        int node = n0 + e; if (node >= NN) node = 0;
        float4 v = ((const float4*)(aggMsg + (long)node * 128))[k4];
        *(s4v*)&feat[e][128 + k4 * 4] = pack4(v.x, v.y, v.z, v.w);
    }
    __syncthreads();

    const int lane = tid & 63;
    const int wid  = tid >> 6;           // 0..7
    const int t16 = lane & 15, q = lane >> 4;
    const int eRow = wid * 16 + t16;     // 0..127
    const int kq = q * 8;

    f32x4 acc[8];
    #pragma unroll
    for (int mt = 0; mt < 8; mt++) acc[mt] = (f32x4){0.f, 0.f, 0.f, 0.f};
    for (int k0 = 0; k0 < 256; k0 += 32) {
        s8v bf = *(const s8v*)&feat[eRow][k0 + kq];
        #pragma unroll
        for (int mt = 0; mt < 8; mt++) {
            s8v af = *(const s8v*)(wn1t + (mt * 16 + t16) * 256 + k0 + kq);
            acc[mt] = __builtin_amdgcn_mfma_f32_16x16x32_bf16(af, bf, acc[mt], 0, 0, 0);
        }
    }
    s4v hres[8];
    #pragma unroll
    for (int mt = 0; mt < 8; mt++) hres[mt] = *(const s4v*)&feat[eRow][mt * 16 + q * 4];
    #pragma unroll
    for (int mt = 0; mt < 8; mt++) {
        int jb = mt * 16 + q * 4;
        *(s4v*)&feat[eRow][jb] = pack4(fsilu(acc[mt][0] + s_bn1[jb + 0]),
                                       fsilu(acc[mt][1] + s_bn1[jb + 1]),
                                       fsilu(acc[mt][2] + s_bn1[jb + 2]),
                                       fsilu(acc[mt][3] + s_bn1[jb + 3]));
    }

    f32x4 acc2[8];
    #pragma unroll
    for (int mt = 0; mt < 8; mt++) acc2[mt] = (f32x4){0.f, 0.f, 0.f, 0.f};
    for (int k0 = 0; k0 < 128; k0 += 32) {
        s8v bf = *(const s8v*)&feat[eRow][k0 + kq];
        #pragma unroll
        for (int mt = 0; mt < 8; mt++) {
            s8v af = *(const s8v*)(wn2t + (mt * 16 + t16) * 128 + k0 + kq);
            acc2[mt] = __builtin_amdgcn_mfma_f32_16x16x32_bf16(af, bf, acc2[mt], 0, 0, 0);
        }
    }
    float zsum = 0.f, zsq = 0.f;
    #pragma unroll
    for (int mt = 0; mt < 8; mt++) {
        #pragma unroll
        for (int r = 0; r < 4; r++) {
            int j = mt * 16 + q * 4 + r;
            float z = b2f(hres[mt][r]) + acc2[mt][r] + s_bn2[j];
            acc2[mt][r] = z;
            zsum += z;
            zsq += z * z;
        }
    }
    zsum += __shfl_xor(zsum, 16); zsum += __shfl_xor(zsum, 32);
    zsq  += __shfl_xor(zsq, 16);  zsq  += __shfl_xor(zsq, 32);
    float mu = zsum * (1.f / 128.f);
    float var = zsq * (1.f / 128.f) - mu * mu;
    float rstd = rsqrtf(fmaxf(var, 0.f) + 1e-5f);
    int node = n0 + eRow;
    if (node < NN) {
        if (outf32) {
            float* o = (float*)out + (long)node * 128;
            #pragma unroll
            for (int mt = 0; mt < 8; mt++) {
                int jb = mt * 16 + q * 4;
                float4 pk;
                pk.x = (acc2[mt][0] - mu) * rstd * s_g[jb + 0] + s_b[jb + 0];
                pk.y = (acc2[mt][1] - mu) * rstd * s_g[jb + 1] + s_b[jb + 1];
                pk.z = (acc2[mt][2] - mu) * rstd * s_g[jb + 2] + s_b[jb + 2];
                pk.w = (acc2[mt][3] - mu) * rstd * s_g[jb + 3] + s_b[jb + 3];
                *(float4*)&o[jb] = pk;
            }
        } else {
            short* o = (short*)out + (long)node * 128;
            #pragma unroll
            for (int mt = 0; mt < 8; mt++) {
                int jb = mt * 16 + q * 4;
                s4v pk = pack4((acc2[mt][0] - mu) * rstd * s_g[jb + 0] + s_b[jb + 0],
                               (acc2[mt][1] - mu) * rstd * s_g[jb + 1] + s_b[jb + 1],
                               (acc2[mt][2] - mu) * rstd * s_g[jb + 2] + s_b[jb + 2],
                               (acc2[mt][3] - mu) * rstd * s_g[jb + 3] + s_b[jb + 3]);
                *(s4v*)&o[jb] = pk;
            }
        }
    }
}

// ---------------- launch ----------------
extern "C" void kernel_launch(void* const* d_in, const int* in_sizes, int n_in,
                              void* d_out, int out_size, void* d_ws, size_t ws_size,
                              hipStream_t stream) {
    const void* h    = d_in[0];
    const void* x    = d_in[1];
    const void* ei   = d_in[2];
    const void* dist = d_in[3];
    const void* We1  = d_in[4];
    const void* be1  = d_in[5];
    const void* We2  = d_in[6];
    const void* be2  = d_in[7];
    const void* Wa   = d_in[8];
    const void* ba   = d_in[9];
    const void* Wn1  = d_in[10];
    const void* bn1  = d_in[11];
    const void* Wn2  = d_in[12];
    const void* bn2  = d_in[13];
    const void* Wc1  = d_in[14];
    const void* bc1  = d_in[15];
    const void* Wc2  = d_in[16];
    const void* gmma = d_in[17];
    const void* beta = d_in[18];

    char* ws = (char*)d_ws;
    int*   flags   = (int*)ws;                          // @0
    short* we1tt   = (short*)(ws + 1024);               // 65536
    short* we2t    = (short*)(ws + 66560);              // 32768
    short* wc1t    = (short*)(ws + 99328);              // 32768
    short* wn1t    = (short*)(ws + 132096);             // 65536
    short* wn2t    = (short*)(ws + 197632);             // 32768
    float* biasbuf = (float*)(ws + 230400);             // 5632
    short* p12     = (short*)(ws + 236544);             // 25.6 MB -> 25836544
    float* aggMsg  = (float*)(ws + 25836544);           // 25.6 MB -> 51436544
    float* aggCoord= (float*)(ws + 51436544);           // 0.6 MB  -> 52036544
    int*   cnt     = (int*)(ws + 52036544);             // 0.2 MB  -> 52236544 (zeroed by memset)
    int*   fillptr = (int*)(ws + 52236544);             // 0.2 MB  -> 52436544
    // d_out scratch (consumed by edge_kernel BEFORE node/xnew overwrite d_out):
    // epack int4[800000] = 12.8MB (<= 13.1MB bf16-out lower bound)
    int4*  epack   = (int4*)d_out;

    // memset covers aggMsg + aggCoord + cnt (contiguous: NN*128 + NN*3 + NN floats)
    hipMemsetAsync(aggMsg, 0, (size_t)(NN * 128 + NN * 3 + NN) * sizeof(float), stream);
    detect_kernel<<<1, 256, 0, stream>>>((const unsigned*)h, (const unsigned*)ei, flags);
    prep_hist_kernel<<<PREPB + HISTB, 256, 0, stream>>>(We1, We2, Wc1, Wn1, Wn2,
                                                        be1, be2, bc1, Wa, ba, Wc2,
                                                        bn1, bn2, gmma, beta, ei, flags,
                                                        we1tt, we2t, wc1t, wn1t, wn2t,
                                                        biasbuf, cnt);
    scan_kernel<<<1, 1024, 0, stream>>>(cnt, fillptr);
    p12_scatter_kernel<<<P12B + SCATB, 512, 0, stream>>>(h, flags, we1tt, p12,
                                                         ei, dist, fillptr, epack);
    edge_kernel<<<EE / ETILE, 512, 0, stream>>>(p12, x, epack, flags,
                                                we2t, wc1t, biasbuf, aggMsg, aggCoord);
    node_xnew_kernel<<<NODEB + XNEWB, 512, 0, stream>>>(h, aggMsg, wn1t, wn2t, biasbuf,
                                                        flags, x, aggCoord, d_out);
}

// Round 9
// 638.479 us; speedup vs baseline: 1.4400x; 1.2249x over previous
//
#include <hip/hip_runtime.h>
#include <hip/hip_bf16.h>
#include <stdint.h>

// ---------------- constants ----------------
#define NN 50000
#define EE 800000
#define HD 128
#define ETILE 256
#define PREPB 769
#define HISTB 3125   // (EE+255)/256
#define P12B  196    // (NN+255)/256
#define SCATB 1563   // (EE+511)/512
#define NODEB 391    // (NN+127)/128
#define XNEWB 293    // (NN*3+511)/512

typedef __attribute__((ext_vector_type(8))) short s8v;   // 8 bf16 (4 VGPRs) mfma A/B frag
typedef __attribute__((ext_vector_type(4))) short s4v;   // 4 bf16 (8B)
typedef __attribute__((ext_vector_type(4))) float f32x4; // mfma C/D frag

__device__ inline float b2f(short s) {
    unsigned u = ((unsigned)(unsigned short)s) << 16;
    return __builtin_bit_cast(float, u);
}
__device__ inline short bf16r(float f) {
    unsigned u = __builtin_bit_cast(unsigned, f);
    unsigned r = (u + 0x7fffu + ((u >> 16) & 1u)) >> 16;
    return (short)r;
}
__device__ inline s4v pack4(float a, float b, float c, float d) {
    union { __hip_bfloat162 h2[2]; s4v v; } u;
    u.h2[0] = __float22bfloat162_rn(make_float2(a, b));
    u.h2[1] = __float22bfloat162_rn(make_float2(c, d));
    return u.v;
}
__device__ inline s8v pack8(const float* v) {
    union { __hip_bfloat162 h2[4]; s8v v8; } u;
    #pragma unroll
    for (int i = 0; i < 4; i++) u.h2[i] = __float22bfloat162_rn(make_float2(v[2*i], v[2*i+1]));
    return u.v8;
}
// R14: v_rcp_f32 (~1 ulp) instead of full-precision div sequence; bf16 output
// tolerates this trivially. Cuts ~8 VALU ops per silu/sigmoid.
__device__ inline float frcp(float x) { return __builtin_amdgcn_rcpf(x); }
__device__ inline float fsilu(float v) { return v * frcp(1.f + __expf(-v)); }

__device__ inline float ldw(const void* p, long i, bool f32) {
    return f32 ? ((const float*)p)[i] : b2f(((const short*)p)[i]);
}
__device__ inline short ldb(const void* p, long i, bool f32) {
    return f32 ? bf16r(((const float*)p)[i]) : ((const short*)p)[i];
}
__device__ inline int ldi(const void* p, long i, bool i64) {
    return i64 ? (int)((const long long*)p)[i] : ((const int*)p)[i];
}

// ---------------- dtype detection ----------------
__global__ void detect_kernel(const unsigned* __restrict__ h_raw,
                              const unsigned* __restrict__ ei_raw, int* flags) {
    __shared__ int cnt_f32, cnt_nz;
    int t = threadIdx.x;
    if (t == 0) { cnt_f32 = 0; cnt_nz = 0; }
    __syncthreads();
    unsigned u = h_raw[t];
    unsigned ex = (u >> 23) & 0xFFu;
    int isf = (ex >= 100u && ex <= 150u) ? 1 : 0;
    unsigned w = ei_raw[2 * t + 1];
    int nz = (w != 0u) ? 1 : 0;
    atomicAdd(&cnt_f32, isf);
    atomicAdd(&cnt_nz, nz);
    __syncthreads();
    if (t == 0) {
        flags[0] = (cnt_f32 >= 128) ? 1 : 0;
        flags[1] = (cnt_nz < 8) ? 1 : 0;
    }
}

// ---------------- fused: prep_weights (blocks 0..768) || hist (blocks 769..3893) ----------
__global__ __launch_bounds__(256)
void prep_hist_kernel(const void* we1, const void* we2, const void* wc1,
                      const void* wn1, const void* wn2,
                      const void* be1, const void* be2, const void* bc1,
                      const void* wa, const void* ba, const void* wc2,
                      const void* bn1, const void* bn2,
                      const void* gmma, const void* beta,
                      const void* __restrict__ ei,
                      const int* __restrict__ flags,
                      short* __restrict__ we1tt, short* __restrict__ we2t,
                      short* __restrict__ wc1t, short* __restrict__ wn1t,
                      short* __restrict__ wn2t, float* __restrict__ biasbuf,
                      int* __restrict__ cnt) {
    bool f32 = flags[0] != 0;
    int b = blockIdx.x, t = threadIdx.x;
    if (b >= PREPB) {   // ---- hist part ----
        int e = (b - PREPB) * 256 + t;
        if (e < EE) atomicAdd(&cnt[ldi(ei, (long)EE + e, flags[1] != 0)], 1);
        return;
    }
    if (b < 256) {
        if (t < 128) we1tt[b * 128 + t] = ldb(we1, (long)((b < 128 ? t : t + 128)) * 128 + (b & 127), f32);
    } else if (b < 384) {
        int j = b - 256; if (t < 128) we2t[j * 128 + t] = ldb(we2, t * 128 + j, f32);
    } else if (b < 512) {
        int j = b - 384; if (t < 128) wc1t[j * 128 + t] = ldb(wc1, t * 128 + j, f32);
    } else if (b < 640) {
        int j = b - 512; wn1t[j * 256 + t] = ldb(wn1, t * 128 + j, f32);   // j in [0,128)
    } else if (b < 768) {
        int j = b - 640; if (t < 128) wn2t[j * 128 + t] = ldb(wn2, t * 128 + j, f32);
    } else if (t < 128) {
        biasbuf[t]         = ldw(be1, t, f32);
        biasbuf[128 + t]   = ldw(be2, t, f32);
        biasbuf[256 + t]   = ldw(bc1, t, f32);
        biasbuf[384 + t]   = ldw(wa, t, f32);
        biasbuf[512 + t]   = ldw(wc2, t, f32);
        biasbuf[768 + t]   = ldw(bn1, t, f32);
        biasbuf[896 + t]   = ldw(bn2, t, f32);
        biasbuf[1024 + t]  = ldw(gmma, t, f32);
        biasbuf[1152 + t]  = ldw(beta, t, f32);
        biasbuf[1280 + t]  = ldw(we1, 256 * 128 + t, f32);   // We1 dist row
        if (t == 0) biasbuf[640] = ldw(ba, 0, f32);
    }
}

// ---------------- exclusive scan of cnt[50000] -> fillptr ----------------
__global__ __launch_bounds__(1024)
void scan_kernel(const int* __restrict__ cnt, int* __restrict__ fillptr) {
    __shared__ int psum[1024];
    const int CH = 49;
    int t = threadIdx.x;
    int base = t * CH;
    int s = 0;
    for (int i = 0; i < CH; i++) { int idx = base + i; if (idx < NN) s += cnt[idx]; }
    psum[t] = s;
    __syncthreads();
    for (int off = 1; off < 1024; off <<= 1) {
        int v = psum[t];
        int add = (t >= off) ? psum[t - off] : 0;
        __syncthreads();
        psum[t] = v + add;
        __syncthreads();
    }
    int running = (t > 0) ? psum[t - 1] : 0;
    for (int i = 0; i < CH; i++) {
        int idx = base + i;
        if (idx < NN) { fillptr[idx] = running; running += cnt[idx]; }
    }
}

// ---------------- fused: p12 (blocks 0..195) || scatter (196..1758) ----------
__global__ __launch_bounds__(512, 4)
void p12_scatter_kernel(const void* __restrict__ hraw, const int* __restrict__ flags,
                        const short* __restrict__ we1tt, short* __restrict__ p12,
                        const void* __restrict__ ei, const void* __restrict__ dist,
                        int* __restrict__ fillptr, int4* __restrict__ epack) {
    const int tid = threadIdx.x;
    if (blockIdx.x >= P12B) {   // ---- scatter part ----
        int e = (int)(blockIdx.x - P12B) * 512 + tid;
        if (e < EE) {
            bool i64 = flags[1] != 0;
            bool f32 = flags[0] != 0;
            int r = ldi(ei, e, i64);
            int c = ldi(ei, (long)EE + e, i64);
            int pos = atomicAdd(&fillptr[c], 1);
            int4 v;
            v.x = r; v.y = c;
            v.z = __builtin_bit_cast(int, ldw(dist, e, f32));
            v.w = 0;
            epack[pos] = v;
        }
        return;
    }
    // ---- p12 part: 256-node tile, 8 waves x dual 16-row subtiles ----
    __shared__ short ht[256][136];
    const int n0 = blockIdx.x * 256;
    const bool f32 = flags[0] != 0;
    #pragma unroll
    for (int k = 0; k < 8; k++) {
        int s = tid + 512 * k;
        int e = s >> 4, c8 = s & 15;
        int node = n0 + e; if (node >= NN) node = 0;
        if (f32) {
            const float* src = (const float*)hraw + (long)node * 128 + c8 * 8;
            float4 v0 = *(const float4*)src, v1 = *(const float4*)(src + 4);
            float vv[8] = {v0.x, v0.y, v0.z, v0.w, v1.x, v1.y, v1.z, v1.w};
            *(s8v*)&ht[e][c8 * 8] = pack8(vv);
        } else {
            uint4 v = *(const uint4*)((const short*)hraw + (long)node * 128 + c8 * 8);
            *(uint4*)&ht[e][c8 * 8] = v;
        }
    }
    __syncthreads();
    const int lane = tid & 63, wid = tid >> 6, t16 = lane & 15, q = lane >> 4, kq = q * 8;
    const int rA = wid * 32 + t16, rB = rA + 16;
    const int ndA = n0 + rA, ndB = n0 + rB;

    // P1 half (We1 rows 0..127)
    f32x4 aA[8], aB[8];
    #pragma unroll
    for (int mt = 0; mt < 8; mt++) { aA[mt] = (f32x4){0.f,0.f,0.f,0.f}; aB[mt] = (f32x4){0.f,0.f,0.f,0.f}; }
    for (int k0 = 0; k0 < 128; k0 += 32) {
        s8v bfA = *(const s8v*)&ht[rA][k0 + kq];
        s8v bfB = *(const s8v*)&ht[rB][k0 + kq];
        #pragma unroll
        for (int mt = 0; mt < 8; mt++) {
            s8v af = *(const s8v*)(we1tt + (mt * 16 + t16) * 128 + k0 + kq);
            aA[mt] = __builtin_amdgcn_mfma_f32_16x16x32_bf16(af, bfA, aA[mt], 0, 0, 0);
            aB[mt] = __builtin_amdgcn_mfma_f32_16x16x32_bf16(af, bfB, aB[mt], 0, 0, 0);
        }
    }
    if (ndA < NN) {
        #pragma unroll
        for (int mt = 0; mt < 8; mt++) {
            int j = mt * 16 + q * 4;
            *(s4v*)(p12 + (long)ndA * 256 + j) = pack4(aA[mt][0], aA[mt][1], aA[mt][2], aA[mt][3]);
        }
    }
    if (ndB < NN) {
        #pragma unroll
        for (int mt = 0; mt < 8; mt++) {
            int j = mt * 16 + q * 4;
            *(s4v*)(p12 + (long)ndB * 256 + j) = pack4(aB[mt][0], aB[mt][1], aB[mt][2], aB[mt][3]);
        }
    }

    // P2 half (We1 rows 128..255)
    #pragma unroll
    for (int mt = 0; mt < 8; mt++) { aA[mt] = (f32x4){0.f,0.f,0.f,0.f}; aB[mt] = (f32x4){0.f,0.f,0.f,0.f}; }
    for (int k0 = 0; k0 < 128; k0 += 32) {
        s8v bfA = *(const s8v*)&ht[rA][k0 + kq];
        s8v bfB = *(const s8v*)&ht[rB][k0 + kq];
        #pragma unroll
        for (int mt = 0; mt < 8; mt++) {
            s8v af = *(const s8v*)(we1tt + (128 + mt * 16 + t16) * 128 + k0 + kq);
            aA[mt] = __builtin_amdgcn_mfma_f32_16x16x32_bf16(af, bfA, aA[mt], 0, 0, 0);
            aB[mt] = __builtin_amdgcn_mfma_f32_16x16x32_bf16(af, bfB, aB[mt], 0, 0, 0);
        }
    }
    if (ndA < NN) {
        #pragma unroll
        for (int mt = 0; mt < 8; mt++) {
            int j = mt * 16 + q * 4;
            *(s4v*)(p12 + (long)ndA * 256 + 128 + j) = pack4(aA[mt][0], aA[mt][1], aA[mt][2], aA[mt][3]);
        }
    }
    if (ndB < NN) {
        #pragma unroll
        for (int mt = 0; mt < 8; mt++) {
            int j = mt * 16 + q * 4;
            *(s4v*)(p12 + (long)ndB * 256 + 128 + j) = pack4(aB[mt][0], aB[mt][1], aB[mt][2], aB[mt][3]);
        }
    }
}

// ---------------- fused edge kernel (R11-proven config: ETILE=256, 512 thr) ----------------
__global__ __launch_bounds__(512, 4)
void edge_kernel(const short* __restrict__ p12,
                 const void* __restrict__ x,
                 const int4* __restrict__ epack,
                 const int* __restrict__ flags,
                 const short* __restrict__ we2t, const short* __restrict__ wc1t,
                 const float* __restrict__ biasbuf,
                 float* __restrict__ aggMsg, float* __restrict__ aggCoord) {
    __shared__ short msgbuf[ETILE][136];
    __shared__ float s_rel[ETILE][3];
    __shared__ float s_cvec[ETILE][3];
    __shared__ int   s_col[ETILE];
    __shared__ float s_be2[128], s_wa[128], s_bc1[128], s_wc2[128];
    __shared__ float s_ba;

    const int tid = threadIdx.x;
    const int e0 = blockIdx.x * ETILE;
    const bool f32 = flags[0] != 0;

    const int jb = (tid & 15) * 8;
    float wv[8], bv[8];
    *(float4*)&wv[0] = *(const float4*)(biasbuf + 1280 + jb);
    *(float4*)&wv[4] = *(const float4*)(biasbuf + 1280 + jb + 4);
    *(float4*)&bv[0] = *(const float4*)(biasbuf + jb);
    *(float4*)&bv[4] = *(const float4*)(biasbuf + jb + 4);

    // staging: msg1 = silu(P1[row] + P2[col] + dist*w256 + be1); 1 packed load/edge
    #pragma unroll
    for (int k = 0; k < 8; k++) {
        int e = (tid >> 4) + 32 * k;
        int4 rc = epack[e0 + e];
        float de = __builtin_bit_cast(float, rc.z);
        s8v a = *(const s8v*)(p12 + ((long)rc.x << 8) + jb);
        s8v b = *(const s8v*)(p12 + ((long)rc.y << 8) + 128 + jb);
        float vv[8];
        #pragma unroll
        for (int i = 0; i < 8; i++)
            vv[i] = fsilu(b2f(a[i]) + b2f(b[i]) + de * wv[i] + bv[i]);
        *(s8v*)&msgbuf[e][jb] = pack8(vv);
    }

    if (tid < ETILE) {
        int4 rc = epack[e0 + tid];
        s_col[tid] = rc.y;
        #pragma unroll
        for (int i = 0; i < 3; i++)
            s_rel[tid][i] = ldw(x, (long)rc.x * 3 + i, f32) - ldw(x, (long)rc.y * 3 + i, f32);
    }
    if (tid < 128) {
        s_be2[tid] = biasbuf[128 + tid];
        s_wa[tid]  = biasbuf[384 + tid];
        s_bc1[tid] = biasbuf[256 + tid];
        s_wc2[tid] = biasbuf[512 + tid];
    }
    if (tid == 0) s_ba = biasbuf[640];
    __syncthreads();

    const int lane = tid & 63;
    const int wid  = tid >> 6;
    const int t16 = lane & 15, q = lane >> 4;
    const int rA = wid * 32 + t16;
    const int rB = rA + 16;
    const int kq = q * 8;

    // ---- GEMM2': msg = We2T . msg1 + be2, two row-subtiles sharing af ----
    f32x4 a2A[8], a2B[8];
    #pragma unroll
    for (int mt = 0; mt < 8; mt++) { a2A[mt] = (f32x4){0.f,0.f,0.f,0.f}; a2B[mt] = (f32x4){0.f,0.f,0.f,0.f}; }
    for (int k0 = 0; k0 < 128; k0 += 32) {
        s8v bfA = *(const s8v*)&msgbuf[rA][k0 + kq];
        s8v bfB = *(const s8v*)&msgbuf[rB][k0 + kq];
        #pragma unroll
        for (int mt = 0; mt < 8; mt++) {
            s8v af = *(const s8v*)(we2t + (mt * 16 + t16) * 128 + k0 + kq);
            a2A[mt] = __builtin_amdgcn_mfma_f32_16x16x32_bf16(af, bfA, a2A[mt], 0, 0, 0);
            a2B[mt] = __builtin_amdgcn_mfma_f32_16x16x32_bf16(af, bfB, a2B[mt], 0, 0, 0);
        }
    }
    float pA = 0.f, pB = 0.f;
    #pragma unroll
    for (int mt = 0; mt < 8; mt++) {
        #pragma unroll
        for (int r = 0; r < 4; r++) {
            int j = mt * 16 + q * 4 + r;
            a2A[mt][r] += s_be2[j];
            a2B[mt][r] += s_be2[j];
            pA += a2A[mt][r] * s_wa[j];
            pB += a2B[mt][r] * s_wa[j];
        }
    }
    pA += __shfl_xor(pA, 16); pA += __shfl_xor(pA, 32);
    pB += __shfl_xor(pB, 16); pB += __shfl_xor(pB, 32);
    float attnA = frcp(1.f + __expf(-(pA + s_ba)));
    float attnB = frcp(1.f + __expf(-(pB + s_ba)));
    #pragma unroll
    for (int mt = 0; mt < 8; mt++) {
        int jbw = mt * 16 + q * 4;
        *(s4v*)&msgbuf[rA][jbw] = pack4(a2A[mt][0]*attnA, a2A[mt][1]*attnA, a2A[mt][2]*attnA, a2A[mt][3]*attnA);
        *(s4v*)&msgbuf[rB][jbw] = pack4(a2B[mt][0]*attnB, a2B[mt][1]*attnB, a2B[mt][2]*attnB, a2B[mt][3]*attnB);
    }

    // ---- GEMM3': coord_w = silu(Wc1T . msg + bc1) . Wc2, two subtiles sharing af ----
    f32x4 a3A[8], a3B[8];
    #pragma unroll
    for (int mt = 0; mt < 8; mt++) { a3A[mt] = (f32x4){0.f,0.f,0.f,0.f}; a3B[mt] = (f32x4){0.f,0.f,0.f,0.f}; }
    for (int k0 = 0; k0 < 128; k0 += 32) {
        s8v bfA = *(const s8v*)&msgbuf[rA][k0 + kq];
        s8v bfB = *(const s8v*)&msgbuf[rB][k0 + kq];
        #pragma unroll
        for (int mt = 0; mt < 8; mt++) {
            s8v af = *(const s8v*)(wc1t + (mt * 16 + t16) * 128 + k0 + kq);
            a3A[mt] = __builtin_amdgcn_mfma_f32_16x16x32_bf16(af, bfA, a3A[mt], 0, 0, 0);
            a3B[mt] = __builtin_amdgcn_mfma_f32_16x16x32_bf16(af, bfB, a3B[mt], 0, 0, 0);
        }
    }
    float p2A = 0.f, p2B = 0.f;
    #pragma unroll
    for (int mt = 0; mt < 8; mt++) {
        #pragma unroll
        for (int r = 0; r < 4; r++) {
            int j = mt * 16 + q * 4 + r;
            p2A += fsilu(a3A[mt][r] + s_bc1[j]) * s_wc2[j];
            p2B += fsilu(a3B[mt][r] + s_bc1[j]) * s_wc2[j];
        }
    }
    p2A += __shfl_xor(p2A, 16); p2A += __shfl_xor(p2A, 32);
    p2B += __shfl_xor(p2B, 16); p2B += __shfl_xor(p2B, 32);
    if (q == 0) {
        #pragma unroll
        for (int i = 0; i < 3; i++) {
            s_cvec[rA][i] = s_rel[rA][i] * p2A;
            s_cvec[rB][i] = s_rel[rB][i] * p2B;
        }
    }
    __syncthreads();

    // ---- segmented reduce over sorted cols: 4 groups of 64 edges, register-batched ----
    {
        int j = tid & 127;
        int eh = (tid >> 7) * 64;
        int runcol = s_col[eh];
        float racc = 0.f;
        #pragma unroll
        for (int rnd = 0; rnd < 4; rnd++) {
            float mv[16]; int cv[16];
            #pragma unroll
            for (int t = 0; t < 16; t++) {
                int e = eh + rnd * 16 + t;
                mv[t] = b2f(msgbuf[e][j]);
                cv[t] = s_col[e];
            }
            #pragma unroll
            for (int t = 0; t < 16; t++) {
                if (cv[t] != runcol) {
                    unsafeAtomicAdd(&aggMsg[(long)runcol * 128 + j], racc);
                    runcol = cv[t]; racc = 0.f;
                }
                racc += mv[t];
            }
        }
        unsafeAtomicAdd(&aggMsg[(long)runcol * 128 + j], racc);
    }
    if (tid < 96) {
        int i = tid % 3, sl = tid / 3;
        int eh = sl * 8;
        int runcol = s_col[eh];
        float racc = 0.f;
        for (int e = eh; e < eh + 8; e++) {
            int c = s_col[e];
            if (c != runcol) {
                unsafeAtomicAdd(&aggCoord[(long)runcol * 3 + i], racc);
                runcol = c; racc = 0.f;
            }
            racc += s_cvec[e][i];
        }
        unsafeAtomicAdd(&aggCoord[(long)runcol * 3 + i], racc);
    }
}

// ---------------- fused: node (blocks 0..390) || xnew (391..683) ----------------
__global__ __launch_bounds__(512, 4)
void node_xnew_kernel(const void* __restrict__ hraw, const float* __restrict__ aggMsg,
                      const short* __restrict__ wn1t, const short* __restrict__ wn2t,
                      const float* __restrict__ biasbuf, const int* __restrict__ flags,
                      const void* __restrict__ x, const float* __restrict__ aggCoord,
                      void* __restrict__ out) {
    const int tid = threadIdx.x;
    const bool outf32 = flags[0] != 0;
    if (blockIdx.x >= NODEB) {   // ---- xnew part ----
        int i = (int)(blockIdx.x - NODEB) * 512 + tid;
        if (i < NN * 3) {
            float v = ldw(x, i, outf32) + aggCoord[i];
            if (outf32) ((float*)out)[(long)NN * 128 + i] = v;
            else        ((short*)out)[(long)NN * 128 + i] = bf16r(v);
        }
        return;
    }
    __shared__ short feat[128][264];
    __shared__ float s_bn1[128], s_bn2[128], s_g[128], s_b[128];
    const int n0 = blockIdx.x * 128;

    if (tid < 128) {
        s_bn1[tid] = biasbuf[768 + tid];
        s_bn2[tid] = biasbuf[896 + tid];
        s_g[tid]   = biasbuf[1024 + tid];
        s_b[tid]   = biasbuf[1152 + tid];
    }
    #pragma unroll
    for (int k = 0; k < 4; k++) {
        int s = tid + 512 * k;
        int e = s >> 4, c8 = s & 15;
        int node = n0 + e; if (node >= NN) node = 0;
        if (outf32) {
            const float* src = (const float*)hraw + (long)node * 128 + c8 * 8;
            float4 v0 = *(const float4*)src, v1 = *(const float4*)(src + 4);
            float vv[8] = {v0.x, v0.y, v0.z, v0.w, v1.x, v1.y, v1.z, v1.w};
            *(s8v*)&feat[e][c8 * 8] = pack8(vv);
        } else {
            uint4 v = *(const uint4*)((const short*)hraw + (long)node * 128 + c8 * 8);
            *(uint4*)&feat[e][c8 * 8] = v;
        }
    }
    #pragma unroll
    for (int k = 0; k < 8; k++) {
        int s = tid + 512 * k;
        int e = s >> 5, k4 = s & 31;
        int node = n0 + e; if (node >= NN) node = 0;
        float4 v = ((const float4*)(aggMsg + (long)node * 128))[k4];
        *(s4v*)&feat[e][128 + k4 * 4] = pack4(v.x, v.y, v.z, v.w);
    }
    __syncthreads();

    const int lane = tid & 63;
    const int wid  = tid >> 6;           // 0..7
    const int t16 = lane & 15, q = lane >> 4;
    const int eRow = wid * 16 + t16;     // 0..127
    const int kq = q * 8;

    f32x4 acc[8];
    #pragma unroll
    for (int mt = 0; mt < 8; mt++) acc[mt] = (f32x4){0.f, 0.f, 0.f, 0.f};
    for (int k0 = 0; k0 < 256; k0 += 32) {
        s8v bf = *(const s8v*)&feat[eRow][k0 + kq];
        #pragma unroll
        for (int mt = 0; mt < 8; mt++) {
            s8v af = *(const s8v*)(wn1t + (mt * 16 + t16) * 256 + k0 + kq);
            acc[mt] = __builtin_amdgcn_mfma_f32_16x16x32_bf16(af, bf, acc[mt], 0, 0, 0);
        }
    }
    s4v hres[8];
    #pragma unroll
    for (int mt = 0; mt < 8; mt++) hres[mt] = *(const s4v*)&feat[eRow][mt * 16 + q * 4];
    #pragma unroll
    for (int mt = 0; mt < 8; mt++) {
        int jb = mt * 16 + q * 4;
        *(s4v*)&feat[eRow][jb] = pack4(fsilu(acc[mt][0] + s_bn1[jb + 0]),
                                       fsilu(acc[mt][1] + s_bn1[jb + 1]),
                                       fsilu(acc[mt][2] + s_bn1[jb + 2]),
                                       fsilu(acc[mt][3] + s_bn1[jb + 3]));
    }

    f32x4 acc2[8];
    #pragma unroll
    for (int mt = 0; mt < 8; mt++) acc2[mt] = (f32x4){0.f, 0.f, 0.f, 0.f};
    for (int k0 = 0; k0 < 128; k0 += 32) {
        s8v bf = *(const s8v*)&feat[eRow][k0 + kq];
        #pragma unroll
        for (int mt = 0; mt < 8; mt++) {
            s8v af = *(const s8v*)(wn2t + (mt * 16 + t16) * 128 + k0 + kq);
            acc2[mt] = __builtin_amdgcn_mfma_f32_16x16x32_bf16(af, bf, acc2[mt], 0, 0, 0);
        }
    }
    float zsum = 0.f, zsq = 0.f;
    #pragma unroll
    for (int mt = 0; mt < 8; mt++) {
        #pragma unroll
        for (int r = 0; r < 4; r++) {
            int j = mt * 16 + q * 4 + r;
            float z = b2f(hres[mt][r]) + acc2[mt][r] + s_bn2[j];
            acc2[mt][r] = z;
            zsum += z;
            zsq += z * z;
        }
    }
    zsum += __shfl_xor(zsum, 16); zsum += __shfl_xor(zsum, 32);
    zsq  += __shfl_xor(zsq, 16);  zsq  += __shfl_xor(zsq, 32);
    float mu = zsum * (1.f / 128.f);
    float var = zsq * (1.f / 128.f) - mu * mu;
    float rstd = rsqrtf(fmaxf(var, 0.f) + 1e-5f);
    int node = n0 + eRow;
    if (node < NN) {
        if (outf32) {
            float* o = (float*)out + (long)node * 128;
            #pragma unroll
            for (int mt = 0; mt < 8; mt++) {
                int jb = mt * 16 + q * 4;
                float4 pk;
                pk.x = (acc2[mt][0] - mu) * rstd * s_g[jb + 0] + s_b[jb + 0];
                pk.y = (acc2[mt][1] - mu) * rstd * s_g[jb + 1] + s_b[jb + 1];
                pk.z = (acc2[mt][2] - mu) * rstd * s_g[jb + 2] + s_b[jb + 2];
                pk.w = (acc2[mt][3] - mu) * rstd * s_g[jb + 3] + s_b[jb + 3];
                *(float4*)&o[jb] = pk;
            }
        } else {
            short* o = (short*)out + (long)node * 128;
            #pragma unroll
            for (int mt = 0; mt < 8; mt++) {
                int jb = mt * 16 + q * 4;
                s4v pk = pack4((acc2[mt][0] - mu) * rstd * s_g[jb + 0] + s_b[jb + 0],
                               (acc2[mt][1] - mu) * rstd * s_g[jb + 1] + s_b[jb + 1],
                               (acc2[mt][2] - mu) * rstd * s_g[jb + 2] + s_b[jb + 2],
                               (acc2[mt][3] - mu) * rstd * s_g[jb + 3] + s_b[jb + 3]);
                *(s4v*)&o[jb] = pk;
            }
        }
    }
}

// ---------------- launch ----------------
extern "C" void kernel_launch(void* const* d_in, const int* in_sizes, int n_in,
                              void* d_out, int out_size, void* d_ws, size_t ws_size,
                              hipStream_t stream) {
    const void* h    = d_in[0];
    const void* x    = d_in[1];
    const void* ei   = d_in[2];
    const void* dist = d_in[3];
    const void* We1  = d_in[4];
    const void* be1  = d_in[5];
    const void* We2  = d_in[6];
    const void* be2  = d_in[7];
    const void* Wa   = d_in[8];
    const void* ba   = d_in[9];
    const void* Wn1  = d_in[10];
    const void* bn1  = d_in[11];
    const void* Wn2  = d_in[12];
    const void* bn2  = d_in[13];
    const void* Wc1  = d_in[14];
    const void* bc1  = d_in[15];
    const void* Wc2  = d_in[16];
    const void* gmma = d_in[17];
    const void* beta = d_in[18];

    char* ws = (char*)d_ws;
    int*   flags   = (int*)ws;                          // @0
    short* we1tt   = (short*)(ws + 1024);               // 65536
    short* we2t    = (short*)(ws + 66560);              // 32768
    short* wc1t    = (short*)(ws + 99328);              // 32768
    short* wn1t    = (short*)(ws + 132096);             // 65536
    short* wn2t    = (short*)(ws + 197632);             // 32768
    float* biasbuf = (float*)(ws + 230400);             // 5632
    short* p12     = (short*)(ws + 236544);             // 25.6 MB -> 25836544
    float* aggMsg  = (float*)(ws + 25836544);           // 25.6 MB -> 51436544
    float* aggCoord= (float*)(ws + 51436544);           // 0.6 MB  -> 52036544
    int*   cnt     = (int*)(ws + 52036544);             // 0.2 MB  -> 52236544 (zeroed by memset)
    int*   fillptr = (int*)(ws + 52236544);             // 0.2 MB  -> 52436544
    // d_out scratch (consumed by edge_kernel BEFORE node/xnew overwrite d_out):
    // epack int4[800000] = 12.8MB (<= 13.1MB bf16-out lower bound)
    int4*  epack   = (int4*)d_out;

    // memset covers aggMsg + aggCoord + cnt (contiguous: NN*128 + NN*3 + NN floats)
    hipMemsetAsync(aggMsg, 0, (size_t)(NN * 128 + NN * 3 + NN) * sizeof(float), stream);
    detect_kernel<<<1, 256, 0, stream>>>((const unsigned*)h, (const unsigned*)ei, flags);
    prep_hist_kernel<<<PREPB + HISTB, 256, 0, stream>>>(We1, We2, Wc1, Wn1, Wn2,
                                                        be1, be2, bc1, Wa, ba, Wc2,
                                                        bn1, bn2, gmma, beta, ei, flags,
                                                        we1tt, we2t, wc1t, wn1t, wn2t,
                                                        biasbuf, cnt);
    scan_kernel<<<1, 1024, 0, stream>>>(cnt, fillptr);
    p12_scatter_kernel<<<P12B + SCATB, 512, 0, stream>>>(h, flags, we1tt, p12,
                                                         ei, dist, fillptr, epack);
    edge_kernel<<<EE / ETILE, 512, 0, stream>>>(p12, x, epack, flags,
                                                we2t, wc1t, biasbuf, aggMsg, aggCoord);
    node_xnew_kernel<<<NODEB + XNEWB, 512, 0, stream>>>(h, aggMsg, wn1t, wn2t, biasbuf,
                                                        flags, x, aggCoord, d_out);
}